// Round 8
// baseline (373.953 us; speedup 1.0000x reference)
//
#include <hip/hip_runtime.h>

// Problem: B=65536 rows, DIM=256, K=1024 codewords.
// out layout (fp32): [0,16777216) quantize | [16777216] diff | [16777217,+65536) indices
#define NROWSQ   65536
#define NDIM     256
#define NCB      1024
#define DIFF_OFF 16777216
#define IDX_OFF  16777217

// bf16 phase-1 margin on 10-bit-quantized shifted scores (~7 sigma)
#define MARGIN_A 0.35f
// pair-path gate: g1-g3 must exceed MARGIN_A + 2*quant(0.0313) + MARGIN_B + slack
#define MARGIN_A3 (MARGIN_A + 0.075f)
// fp32 phase-2 margin -> below this, numpy-mimic decides.
#define MARGIN_B 1.5e-3f
// positivity shift: score+384 in [~105, ~406]; clamped >=1 for safety.
#define SCORE_SHIFT 384.0f

typedef __attribute__((ext_vector_type(8))) short s16x8;
typedef __attribute__((ext_vector_type(4))) float f32x4;

__device__ __forceinline__ unsigned short f2bf(float f) {
  union { float f; unsigned u; } v; v.f = f;
  return (unsigned short)((v.u + 0x7FFFu + ((v.u >> 16) & 1u)) >> 16);  // RNE
}

// async global->LDS, 16B per lane. LDS dest = wave-uniform base + lane*16.
__device__ __forceinline__ void gll16(const void* g, void* l) {
  __builtin_amdgcn_global_load_lds(
      (const __attribute__((address_space(1))) unsigned int*)g,
      (__attribute__((address_space(3))) unsigned int*)l, 16, 0, 0);
}

__device__ __forceinline__ void top2_merge(float& v1, int& i1, float& v2, int& i2,
                                           float ov1, int oi1, float ov2, int oi2) {
  if (ov1 > v1 || (ov1 == v1 && oi1 < i1)) {
    float nv2 = v1; int ni2 = i1;
    if (ov2 > nv2 || (ov2 == nv2 && oi2 < ni2)) { nv2 = ov2; ni2 = oi2; }
    v1 = ov1; i1 = oi1; v2 = nv2; i2 = ni2;
  } else if (ov1 > v2 || (ov1 == v2 && oi1 < i2)) {
    v2 = ov1; i2 = oi1;
  }
}

// numpy pairwise_sum emulation for a contiguous 128-block (8 accumulators).
__device__ __forceinline__ float np_pairwise128(const float* p) {
  float r0 = p[0], r1 = p[1], r2 = p[2], r3 = p[3];
  float r4 = p[4], r5 = p[5], r6 = p[6], r7 = p[7];
  for (int i = 8; i < 128; i += 8) {
    r0 += p[i];     r1 += p[i + 1]; r2 += p[i + 2]; r3 += p[i + 3];
    r4 += p[i + 4]; r5 += p[i + 5]; r6 += p[i + 6]; r7 += p[i + 7];
  }
  return ((r0 + r1) + (r2 + r3)) + ((r4 + r5) + (r6 + r7));
}

// ---------------- k0a: coalesced tiled transpose E[256][1024] -> embT/cbT ----
// cbT rows are stored with the k1 LDS swizzle PRE-BAKED: 16B chunk at logical
// ushort pos p of row r goes to p ^ ((r&7)<<3).
__global__ void k0a_transpose(const float* __restrict__ E, float* __restrict__ embT,
                              unsigned short* __restrict__ cbT,
                              int* __restrict__ cnts, float* __restrict__ outDiff) {
  __shared__ float T[64][65];
  const int t = threadIdx.x;
  const int kbase = (blockIdx.x & 15) * 64;
  const int dbase = (blockIdx.x >> 4) * 64;
  if (blockIdx.x == 0) {
    if (t < 3) cnts[t] = 0;   // cntP, cntF, cntB
    if (t == 3) *outDiff = 0.f;
  }
  #pragma unroll
  for (int i = 0; i < 4; ++i) {
    const int cid = i * 256 + t;
    const int dl = cid >> 4, kc = cid & 15;
    const float4 v = *(const float4*)(E + (size_t)(dbase + dl) * NCB + kbase + kc * 4);
    T[dl][kc * 4 + 0] = v.x; T[dl][kc * 4 + 1] = v.y;
    T[dl][kc * 4 + 2] = v.z; T[dl][kc * 4 + 3] = v.w;
  }
  __syncthreads();
  #pragma unroll
  for (int i = 0; i < 4; ++i) {
    const int cid = i * 256 + t;
    const int kl = cid >> 4, dc = cid & 15;
    float4 v;
    v.x = T[dc * 4 + 0][kl]; v.y = T[dc * 4 + 1][kl];
    v.z = T[dc * 4 + 2][kl]; v.w = T[dc * 4 + 3][kl];
    *(float4*)(embT + (size_t)(kbase + kl) * NDIM + dbase + dc * 4) = v;
    ushort4 b;
    b.x = f2bf(v.x); b.y = f2bf(v.y); b.z = f2bf(v.z); b.w = f2bf(v.w);
    const int dcol = dbase + dc * 4;                  // logical ushort pos (mult of 4)
    const int sp = dcol ^ ((kl & 7) << 3);            // swizzled pos (XOR bits 3-5)
    *(ushort4*)(cbT + (size_t)(kbase + kl) * NDIM + sp) = b;
  }
}

// ---------------- k0b: esq variants from embT ---------------
__global__ void k0b_esq(const float* __restrict__ embT, float* __restrict__ esq32,
                        float* __restrict__ esqs, float* __restrict__ esqr) {
  const int b = blockIdx.x, t = threadIdx.x;
  if (b < 128) {
    const int col = b * 8 + (t >> 5);
    const int l = t & 31;
    double s = 0.0;
    #pragma unroll
    for (int i = 0; i < 8; ++i) {
      const double v = (double)embT[(size_t)col * NDIM + l + i * 32];
      s += v * v;
    }
    #pragma unroll
    for (int m = 16; m >= 1; m >>= 1) s += __shfl_xor(s, m);
    if (l == 0) {
      esq32[col] = (float)(0.5 * s);
      esqs[col] = (float)(0.5 * s) - SCORE_SHIFT;
    }
  } else {
    __shared__ float Ls[16][260];   // pad 260: 16 lanes stride-260 -> 2-way, free
    const int col0 = (b - 128) * 16;
    #pragma unroll
    for (int i = 0; i < 4; ++i) {
      const int flat = i * 256 + t;          // float4 chunk id, 0..1023
      const int row = flat >> 6, f4 = flat & 63;
      *(float4*)&Ls[row][f4 * 4] =
          *(const float4*)(embT + (size_t)(col0 + row) * NDIM + f4 * 4);
    }
    __syncthreads();
    if (t < 16) {
      float sr = 0.f;
      for (int d = 0; d < NDIM; ++d) {
        const float v = Ls[t][d];
        sr = sr + v * v;        // numpy axis-0 reduce: sequential fp32
      }
      esqr[col0 + t] = sr;
    }
  }
}

// ---------------- k1: codebook-quarter-resident MFMA scores, barrier-free ----
// R7 restructure (resubmitted after infra failure). Every prior k1 sat at
// 99-115us with all pipes <20% busy: the per-tile lockstep
// (stage->vmcnt(0)->barrier->compute->barrier with only 8 waves/CU) was the
// invariant cost. Now: grid 256 = 64 row-slices x 4 col-groups, 512-thread
// blocks (1/CU). The group's 128KB codebook quarter is staged into LDS ONCE;
// after a single barrier the 8 waves free-run 16 iterations of 64 rows with
// NO further synchronization. Per-iter top-3 keys; 16 partial planes written
// to part1 (aliased into outQ, dead before k4 rewrites it).
__global__ __launch_bounds__(512, 2) void k1_scores(
    const float* __restrict__ X, const unsigned short* __restrict__ cbT,
    const float* __restrict__ esqs, int4* __restrict__ part1) {
  __shared__ __align__(16) unsigned short Bs[256 * 256];   // 128 KB quarter
  __shared__ float esq_l[256];
  const int t = threadIdx.x;             // 0..511
  const int lane = t & 63, w = t >> 6;   // 8 waves
  const int l15 = lane & 15, quad = lane >> 4;
  const int grp = blockIdx.x & 3;        // col-group (256 cols)
  const int slice = blockIdx.x >> 2;     // row-slice (1024 rows)
  const int roww = w >> 2;               // 0..1: row-half of the 64-row iter
  const int cq = w & 3;                  // 0..3: 64-col quad within group
  const int swz = (l15 & 7) << 3;        // ushort-index XOR for ds_read

  // stage the 128KB quarter once (pre-swizzled, linear DMA)
  const unsigned short* src = cbT + (size_t)grp * 256 * NDIM;
  #pragma unroll
  for (int i = 0; i < 16; ++i)
    gll16(src + (size_t)(i * 512 + t) * 8, &Bs[(i * 512 + w * 64) * 8]);
  if (t < 256) esq_l[t] = esqs[grp * 256 + t];
  asm volatile("s_waitcnt vmcnt(0)" ::: "memory");
  __syncthreads();      // the ONLY barrier

  for (int j = 0; j < 16; ++j) {
    const int rowbase = slice * 1024 + j * 64 + roww * 32;

    // X fragments for this iter's 32 rows: issue all loads, convert on arrival
    float4 xa[2][8], xb[2][8];
    #pragma unroll
    for (int m = 0; m < 2; ++m) {
      const float* xr = X + (size_t)(rowbase + m * 16 + l15) * NDIM;
      #pragma unroll
      for (int ks = 0; ks < 8; ++ks) {
        xa[m][ks] = *(const float4*)(xr + ks * 32 + quad * 8);
        xb[m][ks] = *(const float4*)(xr + ks * 32 + quad * 8 + 4);
      }
    }
    s16x8 afrag[2][8];
    #pragma unroll
    for (int m = 0; m < 2; ++m)
      #pragma unroll
      for (int ks = 0; ks < 8; ++ks) {
        s16x8 a;
        a[0] = (short)f2bf(xa[m][ks].x); a[1] = (short)f2bf(xa[m][ks].y);
        a[2] = (short)f2bf(xa[m][ks].z); a[3] = (short)f2bf(xa[m][ks].w);
        a[4] = (short)f2bf(xb[m][ks].x); a[5] = (short)f2bf(xb[m][ks].y);
        a[6] = (short)f2bf(xb[m][ks].z); a[7] = (short)f2bf(xb[m][ks].w);
        afrag[m][ks] = a;
      }

    f32x4 acc[2][4];
    #pragma unroll
    for (int m = 0; m < 2; ++m)
      #pragma unroll
      for (int s = 0; s < 4; ++s) acc[m][s] = (f32x4){0.f, 0.f, 0.f, 0.f};

    #pragma unroll
    for (int ks = 0; ks < 8; ++ks) {
      #pragma unroll
      for (int s = 0; s < 4; ++s) {
        const int us = (cq * 64 + s * 16 + l15) * 256 + ((ks * 32 + quad * 8) ^ swz);
        const s16x8 bfr = *(const s16x8*)&Bs[us];
        acc[0][s] = __builtin_amdgcn_mfma_f32_16x16x32_bf16(afrag[0][ks], bfr, acc[0][s], 0, 0, 0);
        acc[1][s] = __builtin_amdgcn_mfma_f32_16x16x32_bf16(afrag[1][ks], bfr, acc[1][s], 0, 0, 0);
      }
    }

    int key1[2][4], key2[2][4], key3[2][4];
    #pragma unroll
    for (int m = 0; m < 2; ++m)
      #pragma unroll
      for (int r = 0; r < 4; ++r) { key1[m][r] = 0; key2[m][r] = 0; key3[m][r] = 0; }

    #pragma unroll
    for (int s = 0; s < 4; ++s) {
      const int lcol = cq * 64 + s * 16 + l15;       // local col in group
      const float eq = esq_l[lcol];
      const int suffix = 1023 - (grp * 256 + lcol);  // global col suffix
      #pragma unroll
      for (int m = 0; m < 2; ++m)
        #pragma unroll
        for (int r = 0; r < 4; ++r) {
          float sc = acc[m][s][r] - eq;
          sc = fmaxf(sc, 1.0f);
          const int key = (__float_as_int(sc) & 0xFFFFFC00) | suffix;
          const int tt = min(key1[m][r], key);
          const int n3 = min(key2[m][r], tt);
          key1[m][r] = max(key1[m][r], key);
          key2[m][r] = max(key2[m][r], tt);
          key3[m][r] = max(key3[m][r], n3);
        }
    }

    // exact top-3 butterfly across 16 lanes (cols of this wave's 64)
    #pragma unroll
    for (int mask = 1; mask <= 8; mask <<= 1) {
      #pragma unroll
      for (int m = 0; m < 2; ++m)
        #pragma unroll
        for (int r = 0; r < 4; ++r) {
          const int a1 = key1[m][r], a2 = key2[m][r], a3 = key3[m][r];
          const int b1 = __shfl_xor(a1, mask);
          const int b2 = __shfl_xor(a2, mask);
          const int b3 = __shfl_xor(a3, mask);
          const int p = min(a1, b1);
          const int q = max(a2, b2);
          key1[m][r] = max(a1, b1);
          key2[m][r] = max(p, q);
          key3[m][r] = max(min(p, q), max(min(a2, b2), max(a3, b3)));
        }
    }

    if (l15 == 0) {
      const size_t plane = (size_t)(grp * 4 + cq) * NROWSQ;
      #pragma unroll
      for (int m = 0; m < 2; ++m)
        #pragma unroll
        for (int r = 0; r < 4; ++r) {
          const int grow = rowbase + m * 16 + quad * 4 + r;
          part1[plane + grow] = make_int4(key1[m][r], key2[m][r], key3[m][r], 0);
        }
    }
  }
}

// ---------------- k1m: 16-plane top-3 merge, write idx, route ---------------
__global__ void k1m_merge(const int4* __restrict__ part1, float* __restrict__ outIdx,
                          int* __restrict__ cnts, int2* __restrict__ listP,
                          int* __restrict__ listF) {
  const int row = blockIdx.x * 256 + threadIdx.x;
  const int4 a0 = part1[row];
  int k1 = a0.x, k2 = a0.y, k3 = a0.z;
  #pragma unroll
  for (int g = 1; g < 16; ++g) {
    const int4 b = part1[(size_t)g * NROWSQ + row];
    const int p = min(k1, b.x);
    const int q = max(k2, b.y);
    const int n1 = max(k1, b.x);
    const int n2 = max(p, q);
    const int n3 = max(min(p, q), max(min(k2, b.y), max(k3, b.z)));
    k1 = n1; k2 = n2; k3 = n3;
  }
  const int c1 = 1023 - (k1 & 1023);
  outIdx[row] = (float)c1;
  const float g1 = __int_as_float(k1 & 0xFFFFFC00);
  const float g2 = __int_as_float(k2 & 0xFFFFFC00);
  if (g1 - g2 < MARGIN_A) {
    const float g3 = __int_as_float(k3 & 0xFFFFFC00);
    if (g1 - g3 > MARGIN_A3) {
      const int c2 = 1023 - (k2 & 1023);
      const int p = atomicAdd(&cnts[0], 1);
      listP[p] = make_int2(row, c1 | (c2 << 16));
    } else {
      const int p = atomicAdd(&cnts[1], 1);
      listF[p] = row;
    }
  }
}

// ---------------- k2p: fp32 pair refine {c1,c2} for most contested rows ------
__global__ __launch_bounds__(256) void k2p_pair(
    const float* __restrict__ X, const float* __restrict__ embT,
    const float* __restrict__ esq32, const int* __restrict__ cnts,
    const int2* __restrict__ listP, float* __restrict__ outIdx,
    int* __restrict__ cntB, int* __restrict__ listB) {
  const int cnt = cnts[0];
  for (int j = blockIdx.x * 256 + threadIdx.x; j < cnt; j += gridDim.x * 256) {
    const int2 e = listP[j];
    const int rid = e.x;
    const int c1 = e.y & 0xFFFF;
    const int c2 = ((unsigned)e.y) >> 16;
    const float* xr = X + (size_t)rid * NDIM;
    const float* e1 = embT + (size_t)c1 * NDIM;
    const float* e2 = embT + (size_t)c2 * NDIM;
    float a1 = 0.f, a2 = 0.f;
    #pragma unroll 4
    for (int dq = 0; dq < 64; ++dq) {
      const float4 x = *(const float4*)(xr + dq * 4);
      const float4 p = *(const float4*)(e1 + dq * 4);
      const float4 q = *(const float4*)(e2 + dq * 4);
      a1 = fmaf(x.x, p.x, a1); a1 = fmaf(x.y, p.y, a1);
      a1 = fmaf(x.z, p.z, a1); a1 = fmaf(x.w, p.w, a1);
      a2 = fmaf(x.x, q.x, a2); a2 = fmaf(x.y, q.y, a2);
      a2 = fmaf(x.z, q.z, a2); a2 = fmaf(x.w, q.w, a2);
    }
    const float s1 = a1 - esq32[c1];
    const float s2 = a2 - esq32[c2];
    float v1, v2; int i1;
    if (s1 > s2 || (s1 == s2 && c1 < c2)) { v1 = s1; i1 = c1; v2 = s2; }
    else                                  { v1 = s2; i1 = c2; v2 = s1; }
    outIdx[rid] = (float)i1;
    if (v1 - v2 < MARGIN_B) { const int p = atomicAdd(cntB, 1); listB[p] = rid; }
  }
}

// ---------------- k2a: fp32 full rescan for the rare deep-tie rows -----------
__global__ __launch_bounds__(256) void k2a_refine(
    const float* __restrict__ X, const float* __restrict__ embT,
    const float* __restrict__ esq, const int* __restrict__ cnts,
    const int* __restrict__ listF, float4* __restrict__ part2) {
  __shared__ float Xs[8][NDIM];
  __shared__ float sv1[4][8], sv2[4][8];
  __shared__ int   si1[4][8], si2[4][8];
  const int t = threadIdx.x;
  const int lane = t & 63, w = t >> 6;
  const int split = blockIdx.x & 3;
  const int col = split * 256 + t;
  const int nslots = gridDim.x >> 2;
  const int cnt = cnts[1];
  const float eqc = esq[col];
  const float* er = embT + (size_t)col * NDIM;

  for (int base = (blockIdx.x >> 2) * 8; base < cnt; base += nslots * 8) {
    const int nrows = min(8, cnt - base);
    __syncthreads();
    for (int r = 0; r < 8; ++r) {
      const int rid = listF[base + min(r, nrows - 1)];
      Xs[r][t] = X[(size_t)rid * NDIM + t];
    }
    __syncthreads();

    float acc[8];
    #pragma unroll
    for (int r = 0; r < 8; ++r) acc[r] = 0.f;

    #pragma unroll 4
    for (int dq = 0; dq < 64; ++dq) {
      const float4 e = *(const float4*)(er + dq * 4);
      #pragma unroll
      for (int r = 0; r < 8; ++r) {
        const float4 x = *(const float4*)(&Xs[r][dq * 4]);
        float a = acc[r];
        a = fmaf(x.x, e.x, a);
        a = fmaf(x.y, e.y, a);
        a = fmaf(x.z, e.z, a);
        a = fmaf(x.w, e.w, a);
        acc[r] = a;
      }
    }

    #pragma unroll
    for (int r = 0; r < 8; ++r) {
      float v1 = acc[r] - eqc, v2 = -3.4e38f;
      int   i1 = col, i2 = 0x7fffffff;
      #pragma unroll
      for (int mask = 1; mask < 64; mask <<= 1) {
        const float ov1 = __shfl_xor(v1, mask); const int oi1 = __shfl_xor(i1, mask);
        const float ov2 = __shfl_xor(v2, mask); const int oi2 = __shfl_xor(i2, mask);
        top2_merge(v1, i1, v2, i2, ov1, oi1, ov2, oi2);
      }
      if (lane == 0) { sv1[w][r] = v1; si1[w][r] = i1; sv2[w][r] = v2; si2[w][r] = i2; }
    }
    __syncthreads();
    if (t < nrows) {
      const int r = t;
      float fv1 = sv1[0][r], fv2 = sv2[0][r]; int fi1 = si1[0][r], fi2 = si2[0][r];
      for (int ww = 1; ww < 4; ++ww)
        top2_merge(fv1, fi1, fv2, fi2, sv1[ww][r], si1[ww][r], sv2[ww][r], si2[ww][r]);
      part2[(size_t)split * NROWSQ + base + r] = make_float4(fv1, (float)fi1, fv2, (float)fi2);
    }
    __syncthreads();
  }
}

// ---------------- k2m: merge k2a 4 splits, write idx, build listB ------------
__global__ void k2m_merge(const float4* __restrict__ part2, const int* __restrict__ cnts,
                          const int* __restrict__ listF, float* __restrict__ outIdx,
                          int* __restrict__ cntB, int* __restrict__ listB) {
  const int cnt = cnts[1];
  for (int j = blockIdx.x * 256 + threadIdx.x; j < cnt; j += gridDim.x * 256) {
    const float4 a = part2[j];
    float v1 = a.x, v2 = a.z; int i1 = (int)a.y, i2 = (int)a.w;
    #pragma unroll
    for (int s = 1; s < 4; ++s) {
      const float4 b = part2[(size_t)s * NROWSQ + j];
      top2_merge(v1, i1, v2, i2, b.x, (int)b.y, b.z, (int)b.w);
    }
    const int rid = listF[j];
    outIdx[rid] = (float)i1;
    if (v1 - v2 < MARGIN_B) { const int p = atomicAdd(cntB, 1); listB[p] = rid; }
  }
}

// ---------------- k2b: reference-mimicking fp32 for near-tied rows -----------
__global__ __launch_bounds__(256) void k2b_mimic(
    const float* __restrict__ X, const float* __restrict__ embT,
    const float* __restrict__ esqr, const int* __restrict__ cntB,
    const int* __restrict__ listB, float* __restrict__ outIdx) {
  __shared__ float Xr[NDIM];
  __shared__ float Psq[NDIM];
  __shared__ float rv[256];
  __shared__ int ri[256];
  const int t = threadIdx.x;
  const int cnt = *cntB;
  for (int j = blockIdx.x; j < cnt; j += gridDim.x) {
    const int rid = listB[j];
    __syncthreads();
    {
      const float x = X[(size_t)rid * NDIM + t];
      Xr[t] = x;
      Psq[t] = x * x;
    }
    __syncthreads();
    const float x_sq = np_pairwise128(Psq) + np_pairwise128(Psq + 128);

    float best = 3.4e38f; int bidx = 0x7fffffff;
    #pragma unroll
    for (int c = 0; c < 4; ++c) {
      const int k = t + c * 256;
      const float* er = embT + (size_t)k * NDIM;
      float acc = 0.f;
      #pragma unroll 8
      for (int dq = 0; dq < 64; ++dq) {
        const float4 e = *(const float4*)(er + dq * 4);
        const float4 x = *(const float4*)(Xr + dq * 4);
        acc = fmaf(x.x, e.x, acc);   // strict d-order chain (OpenBLAS mimic)
        acc = fmaf(x.y, e.y, acc);
        acc = fmaf(x.z, e.z, acc);
        acc = fmaf(x.w, e.w, acc);
      }
      const float dist = (x_sq - 2.0f * acc) + esqr[k];
      if (dist < best || (dist == best && k < bidx)) { best = dist; bidx = k; }
    }
    rv[t] = best; ri[t] = bidx;
    __syncthreads();
    for (int off = 128; off > 0; off >>= 1) {
      if (t < off) {
        if (rv[t + off] < rv[t] || (rv[t + off] == rv[t] && ri[t + off] < ri[t])) {
          rv[t] = rv[t + off]; ri[t] = ri[t + off];
        }
      }
      __syncthreads();
    }
    if (t == 0) outIdx[rid] = (float)ri[0];
  }
}

// ---------------- k4: gather codeword, write quantize, diff atomic -----------
__global__ __launch_bounds__(256) void k4_outputs(
    const float* __restrict__ X, const float* __restrict__ embT,
    const float* __restrict__ idxF, float* __restrict__ outQ,
    float* __restrict__ outDiff) {
  const int t = threadIdx.x;
  const int lane = t & 63, w = t >> 6;
  const int W = blockIdx.x * 4 + w;
  float s = 0.f;
  #pragma unroll
  for (int i = 0; i < 8; ++i) {
    const int r = W + i * 8192;
    const int idx = (int)idxF[r];
    const float4 q = *(const float4*)(embT + idx * NDIM + lane * 4);
    const float4 x = *(const float4*)(X + (size_t)r * NDIM + lane * 4);
    *(float4*)(outQ + (size_t)r * NDIM + lane * 4) = q;
    const float dx = q.x - x.x, dy = q.y - x.y, dz = q.z - x.z, dw = q.w - x.w;
    s += dx * dx + dy * dy + dz * dz + dw * dw;
  }
  #pragma unroll
  for (int mask = 1; mask < 64; mask <<= 1) s += __shfl_xor(s, mask);
  __shared__ float bs[4];
  if (lane == 0) bs[w] = s;
  __syncthreads();
  if (t == 0)
    atomicAdd(outDiff, (bs[0] + bs[1] + bs[2] + bs[3]) * (1.0f / 16777216.0f));
}

// ---------------- launch -----------------------------------------------------
extern "C" void kernel_launch(void* const* d_in, const int* in_sizes, int n_in,
                              void* d_out, int out_size, void* d_ws, size_t ws_size,
                              hipStream_t stream) {
  const float* X = (const float*)d_in[0];     // [65536, 256]
  const float* E = (const float*)d_in[1];     // [256, 1024]
  float* out = (float*)d_out;

  char* ws = (char*)d_ws;                     // ~6.5 MB used
  unsigned short* cbT = (unsigned short*)(ws + 0x000000);  // bf16 swizzled [1024][256] 512KB
  float*  embT  = (float*) (ws + 0x080000);   // fp32 [1024][256] 1MB
  float*  esq32 = (float*) (ws + 0x180000);   // 4KB (hi-prec half-norm)
  float*  esqs  = (float*) (ws + 0x181000);   // 4KB (shifted, for k1 keys)
  float*  esqr  = (float*) (ws + 0x182000);   // 4KB (ref-mimic e_sq)
  int*  cnts  = (int*) (ws + 0x183000);       // [cntP, cntF, cntB]
  int2* listP = (int2*)(ws + 0x183100);       // 512KB (row, c1|c2<<16)
  int*  listF = (int*) (ws + 0x203100);       // 256KB
  int*  listB = (int*) (ws + 0x243100);       // 256KB
  float4* part2 = (float4*)(ws + 0x283100);   // 4 x 65536 x 16B = 4MB

  int* cntB = cnts + 2;

  float* outQ    = out;
  float* outDiff = out + DIFF_OFF;
  float* outIdx  = out + IDX_OFF;

  // part1 (16 planes x 65536 x int4 = 16MB) lives in the outQ region: it is
  // dead after k1m, and k4 fully overwrites outQ at the end.
  int4* part1 = (int4*)outQ;

  k0a_transpose<<<dim3(64), dim3(256), 0, stream>>>(E, embT, cbT, cnts, outDiff);
  k0b_esq<<<dim3(192), dim3(256), 0, stream>>>(embT, esq32, esqs, esqr);
  k1_scores<<<dim3(256), dim3(512), 0, stream>>>(X, cbT, esqs, part1);
  k1m_merge<<<dim3(256), dim3(256), 0, stream>>>(part1, outIdx, cnts, listP, listF);
  k2p_pair<<<dim3(256), dim3(256), 0, stream>>>(X, embT, esq32, cnts, listP,
                                                outIdx, cntB, listB);
  k2a_refine<<<dim3(2048), dim3(256), 0, stream>>>(X, embT, esq32, cnts, listF, part2);
  k2m_merge<<<dim3(64), dim3(256), 0, stream>>>(part2, cnts, listF, outIdx, cntB, listB);
  k2b_mimic<<<dim3(64), dim3(256), 0, stream>>>(X, embT, esqr, cntB, listB, outIdx);
  k4_outputs<<<dim3(2048), dim3(256), 0, stream>>>(X, embT, outIdx, outQ, outDiff);
}

// Round 10
// 302.839 us; speedup vs baseline: 1.2348x; 1.2348x over previous
//
#include <hip/hip_runtime.h>

// Problem: B=65536 rows, DIM=256, K=1024 codewords.
// out layout (fp32): [0,16777216) quantize | [16777216] diff | [16777217,+65536) indices
#define NROWSQ   65536
#define NDIM     256
#define NCB      1024
#define DIFF_OFF 16777216
#define IDX_OFF  16777217

// bf16 phase-1 margin on 10-bit-quantized shifted scores (~7 sigma)
#define MARGIN_A 0.35f
// pair-path gate: g1-g3 must exceed MARGIN_A + 2*quant(0.0313) + MARGIN_B + slack
#define MARGIN_A3 (MARGIN_A + 0.075f)
// fp32 phase-2 margin -> below this, numpy-mimic decides.
#define MARGIN_B 1.5e-3f
// positivity shift: score+384 in [~105, ~406]; clamped >=1 for safety.
#define SCORE_SHIFT 384.0f

typedef __attribute__((ext_vector_type(8))) short s16x8;
typedef __attribute__((ext_vector_type(4))) float f32x4;

__device__ __forceinline__ unsigned short f2bf(float f) {
  union { float f; unsigned u; } v; v.f = f;
  return (unsigned short)((v.u + 0x7FFFu + ((v.u >> 16) & 1u)) >> 16);  // RNE
}

// async global->LDS, 16B per lane. LDS dest = wave-uniform base + lane*16.
__device__ __forceinline__ void gll16(const void* g, void* l) {
  __builtin_amdgcn_global_load_lds(
      (const __attribute__((address_space(1))) unsigned int*)g,
      (__attribute__((address_space(3))) unsigned int*)l, 16, 0, 0);
}

__device__ __forceinline__ void top2_merge(float& v1, int& i1, float& v2, int& i2,
                                           float ov1, int oi1, float ov2, int oi2) {
  if (ov1 > v1 || (ov1 == v1 && oi1 < i1)) {
    float nv2 = v1; int ni2 = i1;
    if (ov2 > nv2 || (ov2 == nv2 && oi2 < ni2)) { nv2 = ov2; ni2 = oi2; }
    v1 = ov1; i1 = oi1; v2 = nv2; i2 = ni2;
  } else if (ov1 > v2 || (ov1 == v2 && oi1 < i2)) {
    v2 = ov1; i2 = oi1;
  }
}

// numpy pairwise_sum emulation for a contiguous 128-block (8 accumulators).
__device__ __forceinline__ float np_pairwise128(const float* p) {
  float r0 = p[0], r1 = p[1], r2 = p[2], r3 = p[3];
  float r4 = p[4], r5 = p[5], r6 = p[6], r7 = p[7];
  for (int i = 8; i < 128; i += 8) {
    r0 += p[i];     r1 += p[i + 1]; r2 += p[i + 2]; r3 += p[i + 3];
    r4 += p[i + 4]; r5 += p[i + 5]; r6 += p[i + 6]; r7 += p[i + 7];
  }
  return ((r0 + r1) + (r2 + r3)) + ((r4 + r5) + (r6 + r7));
}

// ---------------- k0a: coalesced tiled transpose E[256][1024] -> embT/cbT ----
// cbT rows are stored with the k1 LDS swizzle PRE-BAKED: 16B chunk at logical
// ushort pos p of row r goes to p ^ ((r&7)<<3).
__global__ void k0a_transpose(const float* __restrict__ E, float* __restrict__ embT,
                              unsigned short* __restrict__ cbT,
                              int* __restrict__ cnts, float* __restrict__ outDiff) {
  __shared__ float T[64][65];
  const int t = threadIdx.x;
  const int kbase = (blockIdx.x & 15) * 64;
  const int dbase = (blockIdx.x >> 4) * 64;
  if (blockIdx.x == 0) {
    if (t < 3) cnts[t] = 0;   // cntP, cntF, cntB
    if (t == 3) *outDiff = 0.f;
  }
  #pragma unroll
  for (int i = 0; i < 4; ++i) {
    const int cid = i * 256 + t;
    const int dl = cid >> 4, kc = cid & 15;
    const float4 v = *(const float4*)(E + (size_t)(dbase + dl) * NCB + kbase + kc * 4);
    T[dl][kc * 4 + 0] = v.x; T[dl][kc * 4 + 1] = v.y;
    T[dl][kc * 4 + 2] = v.z; T[dl][kc * 4 + 3] = v.w;
  }
  __syncthreads();
  #pragma unroll
  for (int i = 0; i < 4; ++i) {
    const int cid = i * 256 + t;
    const int kl = cid >> 4, dc = cid & 15;
    float4 v;
    v.x = T[dc * 4 + 0][kl]; v.y = T[dc * 4 + 1][kl];
    v.z = T[dc * 4 + 2][kl]; v.w = T[dc * 4 + 3][kl];
    *(float4*)(embT + (size_t)(kbase + kl) * NDIM + dbase + dc * 4) = v;
    ushort4 b;
    b.x = f2bf(v.x); b.y = f2bf(v.y); b.z = f2bf(v.z); b.w = f2bf(v.w);
    const int dcol = dbase + dc * 4;                  // logical ushort pos (mult of 4)
    const int sp = dcol ^ ((kl & 7) << 3);            // swizzled pos (XOR bits 3-5)
    *(ushort4*)(cbT + (size_t)(kbase + kl) * NDIM + sp) = b;
  }
}

// ---------------- k0b: esq variants from embT ---------------
__global__ void k0b_esq(const float* __restrict__ embT, float* __restrict__ esq32,
                        float* __restrict__ esqs, float* __restrict__ esqr) {
  const int b = blockIdx.x, t = threadIdx.x;
  if (b < 128) {
    const int col = b * 8 + (t >> 5);
    const int l = t & 31;
    double s = 0.0;
    #pragma unroll
    for (int i = 0; i < 8; ++i) {
      const double v = (double)embT[(size_t)col * NDIM + l + i * 32];
      s += v * v;
    }
    #pragma unroll
    for (int m = 16; m >= 1; m >>= 1) s += __shfl_xor(s, m);
    if (l == 0) {
      esq32[col] = (float)(0.5 * s);
      esqs[col] = (float)(0.5 * s) - SCORE_SHIFT;
    }
  } else {
    __shared__ float Ls[16][260];   // pad 260: 16 lanes stride-260 -> 2-way, free
    const int col0 = (b - 128) * 16;
    #pragma unroll
    for (int i = 0; i < 4; ++i) {
      const int flat = i * 256 + t;          // float4 chunk id, 0..1023
      const int row = flat >> 6, f4 = flat & 63;
      *(float4*)&Ls[row][f4 * 4] =
          *(const float4*)(embT + (size_t)(col0 + row) * NDIM + f4 * 4);
    }
    __syncthreads();
    if (t < 16) {
      float sr = 0.f;
      for (int d = 0; d < NDIM; ++d) {
        const float v = Ls[t][d];
        sr = sr + v * v;        // numpy axis-0 reduce: sequential fp32
      }
      esqr[col0 + t] = sr;
    }
  }
}

// ---------------- k1: bf16 MFMA scores, X-read-once, 4 blocks/CU -------------
// R9 (resubmitted after infra failure). R8's col-group split re-read X 4x
// (FETCH 136MB) and died on HBM latency at 8 waves/CU. Back to X-read-once
// (each block owns 64 rows x all 1024 cols, keys complete in registers, ONE
// butterfly, fused routing). The lockstep-stall fix is occupancy: single
// 32KB B-buffer + 4KB esq = 36.2KB -> 4 blocks/CU = 16 waves/CU; independent
// blocks sit in different phases, so MFMA/VALU/DMA from different blocks
// co-issue (cross-block role diversity). m=1 per wave (16 rows): afrag 32
// VGPR, total ~95 -> launch_bounds(256,4), no spill (R5 lesson).
__global__ __launch_bounds__(256, 4) void k1_scores(
    const float* __restrict__ X, const unsigned short* __restrict__ cbT,
    const float* __restrict__ esqs, float* __restrict__ outIdx,
    int* __restrict__ cnts, int2* __restrict__ listP, int* __restrict__ listF) {
  __shared__ __align__(16) unsigned short Bs[64 * 256];  // 32 KB, single buffer
  __shared__ float esq_l[1024];
  const int t = threadIdx.x;
  const int lane = t & 63, w = t >> 6;
  const int l15 = lane & 15, quad = lane >> 4;
  const int rowbase = blockIdx.x * 64 + w * 16;
  const int swz = (l15 & 7) << 3;   // ushort-index XOR for ds_read

  // stage tile 0 (8 x 16B per thread, linear DMA into pre-swizzled layout)
  #pragma unroll
  for (int i = 0; i < 8; ++i)
    gll16(cbT + (size_t)(i * 256 + t) * 8, &Bs[(i * 256 + w * 64) * 8]);

  // A fragments: lane holds A[m=l15][k=quad*8+j]; 16 rows per wave, loaded once.
  s16x8 afrag[8];
  {
    const float* xr = X + (size_t)(rowbase + l15) * NDIM;
    #pragma unroll
    for (int ks = 0; ks < 8; ++ks) {
      const float4 xa = *(const float4*)(xr + ks * 32 + quad * 8);
      const float4 xb = *(const float4*)(xr + ks * 32 + quad * 8 + 4);
      s16x8 a;
      a[0] = (short)f2bf(xa.x); a[1] = (short)f2bf(xa.y);
      a[2] = (short)f2bf(xa.z); a[3] = (short)f2bf(xa.w);
      a[4] = (short)f2bf(xb.x); a[5] = (short)f2bf(xb.y);
      a[6] = (short)f2bf(xb.z); a[7] = (short)f2bf(xb.w);
      afrag[ks] = a;
    }
  }

  {
    const float4 e4 = *(const float4*)(esqs + t * 4);
    *(float4*)(esq_l + t * 4) = e4;
  }

  int key1[4], key2[4], key3[4];
  #pragma unroll
  for (int r = 0; r < 4; ++r) { key1[r] = 0; key2[r] = 0; key3[r] = 0; }

  asm volatile("s_waitcnt vmcnt(0)" ::: "memory");
  __syncthreads();      // tile 0 staged, esq_l visible

  for (int nt = 0; nt < 16; ++nt) {
    f32x4 acc[4];
    #pragma unroll
    for (int s = 0; s < 4; ++s) acc[s] = (f32x4){0.f, 0.f, 0.f, 0.f};

    #pragma unroll
    for (int ks = 0; ks < 8; ++ks) {
      #pragma unroll
      for (int s = 0; s < 4; ++s) {
        const int us = (s * 16 + l15) * 256 + ((ks * 32 + quad * 8) ^ swz);
        const s16x8 bfr = *(const s16x8*)&Bs[us];
        acc[s] = __builtin_amdgcn_mfma_f32_16x16x32_bf16(afrag[ks], bfr, acc[s], 0, 0, 0);
      }
    }

    #pragma unroll
    for (int s = 0; s < 4; ++s) {
      const int lcol = nt * 64 + s * 16 + l15;
      const float eq = esq_l[lcol];
      const int suffix = 1023 - lcol;
      #pragma unroll
      for (int r = 0; r < 4; ++r) {
        float sc = acc[s][r] - eq;
        sc = fmaxf(sc, 1.0f);
        const int key = (__float_as_int(sc) & 0xFFFFFC00) | suffix;
        // exact top-3 insert (uses OLD key2 for the slot-3 candidate)
        const int tt = min(key1[r], key);
        const int n3 = min(key2[r], tt);
        key1[r] = max(key1[r], key);
        key2[r] = max(key2[r], tt);
        key3[r] = max(key3[r], n3);
      }
    }

    __syncthreads();    // all waves done reading Bs[nt]
    if (nt < 15) {
      const unsigned short* src = cbT + (size_t)(nt + 1) * (64 * 256);
      #pragma unroll
      for (int i = 0; i < 8; ++i)
        gll16(src + (size_t)(i * 256 + t) * 8, &Bs[(i * 256 + w * 64) * 8]);
      asm volatile("s_waitcnt vmcnt(0)" ::: "memory");
    }
    __syncthreads();    // tile nt+1 staged
  }

  // exact top-3 butterfly across 16 lanes (once, after all tiles)
  #pragma unroll
  for (int mask = 1; mask <= 8; mask <<= 1) {
    #pragma unroll
    for (int r = 0; r < 4; ++r) {
      const int a1 = key1[r], a2 = key2[r], a3 = key3[r];
      const int b1 = __shfl_xor(a1, mask);
      const int b2 = __shfl_xor(a2, mask);
      const int b3 = __shfl_xor(a3, mask);
      const int p = min(a1, b1);
      const int q = max(a2, b2);
      key1[r] = max(a1, b1);
      key2[r] = max(p, q);
      key3[r] = max(min(p, q), max(min(a2, b2), max(a3, b3)));
    }
  }

  // fused routing epilogue: write idx + route contested rows
  if (l15 == 0) {
    #pragma unroll
    for (int r = 0; r < 4; ++r) {
      const int grow = rowbase + quad * 4 + r;
      const int k1v = key1[r], k2v = key2[r], k3v = key3[r];
      const int c1 = 1023 - (k1v & 1023);
      outIdx[grow] = (float)c1;
      const float g1 = __int_as_float(k1v & 0xFFFFFC00);
      const float g2 = __int_as_float(k2v & 0xFFFFFC00);
      if (g1 - g2 < MARGIN_A) {
        const float g3 = __int_as_float(k3v & 0xFFFFFC00);
        if (g1 - g3 > MARGIN_A3) {
          const int c2 = 1023 - (k2v & 1023);
          const int p = atomicAdd(&cnts[0], 1);
          listP[p] = make_int2(grow, c1 | (c2 << 16));
        } else {
          const int p = atomicAdd(&cnts[1], 1);
          listF[p] = grow;
        }
      }
    }
  }
}

// ---------------- k2p: fp32 pair refine {c1,c2} for most contested rows ------
__global__ __launch_bounds__(256) void k2p_pair(
    const float* __restrict__ X, const float* __restrict__ embT,
    const float* __restrict__ esq32, const int* __restrict__ cnts,
    const int2* __restrict__ listP, float* __restrict__ outIdx,
    int* __restrict__ cntB, int* __restrict__ listB) {
  const int cnt = cnts[0];
  for (int j = blockIdx.x * 256 + threadIdx.x; j < cnt; j += gridDim.x * 256) {
    const int2 e = listP[j];
    const int rid = e.x;
    const int c1 = e.y & 0xFFFF;
    const int c2 = ((unsigned)e.y) >> 16;
    const float* xr = X + (size_t)rid * NDIM;
    const float* e1 = embT + (size_t)c1 * NDIM;
    const float* e2 = embT + (size_t)c2 * NDIM;
    float a1 = 0.f, a2 = 0.f;
    #pragma unroll 4
    for (int dq = 0; dq < 64; ++dq) {
      const float4 x = *(const float4*)(xr + dq * 4);
      const float4 p = *(const float4*)(e1 + dq * 4);
      const float4 q = *(const float4*)(e2 + dq * 4);
      a1 = fmaf(x.x, p.x, a1); a1 = fmaf(x.y, p.y, a1);
      a1 = fmaf(x.z, p.z, a1); a1 = fmaf(x.w, p.w, a1);
      a2 = fmaf(x.x, q.x, a2); a2 = fmaf(x.y, q.y, a2);
      a2 = fmaf(x.z, q.z, a2); a2 = fmaf(x.w, q.w, a2);
    }
    const float s1 = a1 - esq32[c1];
    const float s2 = a2 - esq32[c2];
    float v1, v2; int i1;
    if (s1 > s2 || (s1 == s2 && c1 < c2)) { v1 = s1; i1 = c1; v2 = s2; }
    else                                  { v1 = s2; i1 = c2; v2 = s1; }
    outIdx[rid] = (float)i1;
    if (v1 - v2 < MARGIN_B) { const int p = atomicAdd(cntB, 1); listB[p] = rid; }
  }
}

// ---------------- k2a: fp32 full rescan for the rare deep-tie rows -----------
__global__ __launch_bounds__(256) void k2a_refine(
    const float* __restrict__ X, const float* __restrict__ embT,
    const float* __restrict__ esq, const int* __restrict__ cnts,
    const int* __restrict__ listF, float4* __restrict__ part2) {
  __shared__ float Xs[8][NDIM];
  __shared__ float sv1[4][8], sv2[4][8];
  __shared__ int   si1[4][8], si2[4][8];
  const int t = threadIdx.x;
  const int lane = t & 63, w = t >> 6;
  const int split = blockIdx.x & 3;
  const int col = split * 256 + t;
  const int nslots = gridDim.x >> 2;
  const int cnt = cnts[1];
  const float eqc = esq[col];
  const float* er = embT + (size_t)col * NDIM;

  for (int base = (blockIdx.x >> 2) * 8; base < cnt; base += nslots * 8) {
    const int nrows = min(8, cnt - base);
    __syncthreads();
    for (int r = 0; r < 8; ++r) {
      const int rid = listF[base + min(r, nrows - 1)];
      Xs[r][t] = X[(size_t)rid * NDIM + t];
    }
    __syncthreads();

    float acc[8];
    #pragma unroll
    for (int r = 0; r < 8; ++r) acc[r] = 0.f;

    #pragma unroll 4
    for (int dq = 0; dq < 64; ++dq) {
      const float4 e = *(const float4*)(er + dq * 4);
      #pragma unroll
      for (int r = 0; r < 8; ++r) {
        const float4 x = *(const float4*)(&Xs[r][dq * 4]);
        float a = acc[r];
        a = fmaf(x.x, e.x, a);
        a = fmaf(x.y, e.y, a);
        a = fmaf(x.z, e.z, a);
        a = fmaf(x.w, e.w, a);
        acc[r] = a;
      }
    }

    #pragma unroll
    for (int r = 0; r < 8; ++r) {
      float v1 = acc[r] - eqc, v2 = -3.4e38f;
      int   i1 = col, i2 = 0x7fffffff;
      #pragma unroll
      for (int mask = 1; mask < 64; mask <<= 1) {
        const float ov1 = __shfl_xor(v1, mask); const int oi1 = __shfl_xor(i1, mask);
        const float ov2 = __shfl_xor(v2, mask); const int oi2 = __shfl_xor(i2, mask);
        top2_merge(v1, i1, v2, i2, ov1, oi1, ov2, oi2);
      }
      if (lane == 0) { sv1[w][r] = v1; si1[w][r] = i1; sv2[w][r] = v2; si2[w][r] = i2; }
    }
    __syncthreads();
    if (t < nrows) {
      const int r = t;
      float fv1 = sv1[0][r], fv2 = sv2[0][r]; int fi1 = si1[0][r], fi2 = si2[0][r];
      for (int ww = 1; ww < 4; ++ww)
        top2_merge(fv1, fi1, fv2, fi2, sv1[ww][r], si1[ww][r], sv2[ww][r], si2[ww][r]);
      part2[(size_t)split * NROWSQ + base + r] = make_float4(fv1, (float)fi1, fv2, (float)fi2);
    }
    __syncthreads();
  }
}

// ---------------- k2m: merge k2a 4 splits, write idx, build listB ------------
__global__ void k2m_merge(const float4* __restrict__ part2, const int* __restrict__ cnts,
                          const int* __restrict__ listF, float* __restrict__ outIdx,
                          int* __restrict__ cntB, int* __restrict__ listB) {
  const int cnt = cnts[1];
  for (int j = blockIdx.x * 256 + threadIdx.x; j < cnt; j += gridDim.x * 256) {
    const float4 a = part2[j];
    float v1 = a.x, v2 = a.z; int i1 = (int)a.y, i2 = (int)a.w;
    #pragma unroll
    for (int s = 1; s < 4; ++s) {
      const float4 b = part2[(size_t)s * NROWSQ + j];
      top2_merge(v1, i1, v2, i2, b.x, (int)b.y, b.z, (int)b.w);
    }
    const int rid = listF[j];
    outIdx[rid] = (float)i1;
    if (v1 - v2 < MARGIN_B) { const int p = atomicAdd(cntB, 1); listB[p] = rid; }
  }
}

// ---------------- k2b: reference-mimicking fp32 for near-tied rows -----------
__global__ __launch_bounds__(256) void k2b_mimic(
    const float* __restrict__ X, const float* __restrict__ embT,
    const float* __restrict__ esqr, const int* __restrict__ cntB,
    const int* __restrict__ listB, float* __restrict__ outIdx) {
  __shared__ float Xr[NDIM];
  __shared__ float Psq[NDIM];
  __shared__ float rv[256];
  __shared__ int ri[256];
  const int t = threadIdx.x;
  const int cnt = *cntB;
  for (int j = blockIdx.x; j < cnt; j += gridDim.x) {
    const int rid = listB[j];
    __syncthreads();
    {
      const float x = X[(size_t)rid * NDIM + t];
      Xr[t] = x;
      Psq[t] = x * x;
    }
    __syncthreads();
    const float x_sq = np_pairwise128(Psq) + np_pairwise128(Psq + 128);

    float best = 3.4e38f; int bidx = 0x7fffffff;
    #pragma unroll
    for (int c = 0; c < 4; ++c) {
      const int k = t + c * 256;
      const float* er = embT + (size_t)k * NDIM;
      float acc = 0.f;
      #pragma unroll 8
      for (int dq = 0; dq < 64; ++dq) {
        const float4 e = *(const float4*)(er + dq * 4);
        const float4 x = *(const float4*)(Xr + dq * 4);
        acc = fmaf(x.x, e.x, acc);   // strict d-order chain (OpenBLAS mimic)
        acc = fmaf(x.y, e.y, acc);
        acc = fmaf(x.z, e.z, acc);
        acc = fmaf(x.w, e.w, acc);
      }
      const float dist = (x_sq - 2.0f * acc) + esqr[k];
      if (dist < best || (dist == best && k < bidx)) { best = dist; bidx = k; }
    }
    rv[t] = best; ri[t] = bidx;
    __syncthreads();
    for (int off = 128; off > 0; off >>= 1) {
      if (t < off) {
        if (rv[t + off] < rv[t] || (rv[t + off] == rv[t] && ri[t + off] < ri[t])) {
          rv[t] = rv[t + off]; ri[t] = ri[t + off];
        }
      }
      __syncthreads();
    }
    if (t == 0) outIdx[rid] = (float)ri[0];
  }
}

// ---------------- k4: gather codeword, write quantize, diff atomic -----------
__global__ __launch_bounds__(256) void k4_outputs(
    const float* __restrict__ X, const float* __restrict__ embT,
    const float* __restrict__ idxF, float* __restrict__ outQ,
    float* __restrict__ outDiff) {
  const int t = threadIdx.x;
  const int lane = t & 63, w = t >> 6;
  const int W = blockIdx.x * 4 + w;
  float s = 0.f;
  #pragma unroll
  for (int i = 0; i < 8; ++i) {
    const int r = W + i * 8192;
    const int idx = (int)idxF[r];
    const float4 q = *(const float4*)(embT + idx * NDIM + lane * 4);
    const float4 x = *(const float4*)(X + (size_t)r * NDIM + lane * 4);
    *(float4*)(outQ + (size_t)r * NDIM + lane * 4) = q;
    const float dx = q.x - x.x, dy = q.y - x.y, dz = q.z - x.z, dw = q.w - x.w;
    s += dx * dx + dy * dy + dz * dz + dw * dw;
  }
  #pragma unroll
  for (int mask = 1; mask < 64; mask <<= 1) s += __shfl_xor(s, mask);
  __shared__ float bs[4];
  if (lane == 0) bs[w] = s;
  __syncthreads();
  if (t == 0)
    atomicAdd(outDiff, (bs[0] + bs[1] + bs[2] + bs[3]) * (1.0f / 16777216.0f));
}

// ---------------- launch -----------------------------------------------------
extern "C" void kernel_launch(void* const* d_in, const int* in_sizes, int n_in,
                              void* d_out, int out_size, void* d_ws, size_t ws_size,
                              hipStream_t stream) {
  const float* X = (const float*)d_in[0];     // [65536, 256]
  const float* E = (const float*)d_in[1];     // [256, 1024]
  float* out = (float*)d_out;

  char* ws = (char*)d_ws;                     // ~6.5 MB used
  unsigned short* cbT = (unsigned short*)(ws + 0x000000);  // bf16 swizzled [1024][256] 512KB
  float*  embT  = (float*) (ws + 0x080000);   // fp32 [1024][256] 1MB
  float*  esq32 = (float*) (ws + 0x180000);   // 4KB (hi-prec half-norm)
  float*  esqs  = (float*) (ws + 0x181000);   // 4KB (shifted, for k1 keys)
  float*  esqr  = (float*) (ws + 0x182000);   // 4KB (ref-mimic e_sq)
  int*  cnts  = (int*) (ws + 0x183000);       // [cntP, cntF, cntB]
  int2* listP = (int2*)(ws + 0x183100);       // 512KB (row, c1|c2<<16)
  int*  listF = (int*) (ws + 0x203100);       // 256KB
  int*  listB = (int*) (ws + 0x243100);       // 256KB
  float4* part2 = (float4*)(ws + 0x283100);   // 4 x 65536 x 16B = 4MB

  int* cntB = cnts + 2;

  float* outQ    = out;
  float* outDiff = out + DIFF_OFF;
  float* outIdx  = out + IDX_OFF;

  k0a_transpose<<<dim3(64), dim3(256), 0, stream>>>(E, embT, cbT, cnts, outDiff);
  k0b_esq<<<dim3(192), dim3(256), 0, stream>>>(embT, esq32, esqs, esqr);
  k1_scores<<<dim3(1024), dim3(256), 0, stream>>>(X, cbT, esqs, outIdx, cnts, listP, listF);
  k2p_pair<<<dim3(256), dim3(256), 0, stream>>>(X, embT, esq32, cnts, listP,
                                                outIdx, cntB, listB);
  k2a_refine<<<dim3(2048), dim3(256), 0, stream>>>(X, embT, esq32, cnts, listF, part2);
  k2m_merge<<<dim3(64), dim3(256), 0, stream>>>(part2, cnts, listF, outIdx, cntB, listB);
  k2b_mimic<<<dim3(64), dim3(256), 0, stream>>>(X, embT, esqr, cntB, listB, outIdx);
  k4_outputs<<<dim3(2048), dim3(256), 0, stream>>>(X, embT, outIdx, outQ, outDiff);
}